// Round 1
// baseline (122.756 us; speedup 1.0000x reference)
//
#include <hip/hip_runtime.h>
#include <math.h>

// Problem constants (from reference)
#define TT_  2048   // T
#define BB   4      // B
#define DD   256    // d
#define NN   256    // n
#define CH   128    // CHUNK
#define NCH  16     // T/CHUNK
#define EPSF 1e-8f

// Workspace layout (float offsets)
#define OFF_W   0            // w  [NCH][BB][CH][NN]  = 2097152
#define OFF_PF  2097152      // pf [NCH][BB][NN]      = 16384
#define OFF_UT  2113536      // UT [NCH][BB][NN][DD]  = 4194304
#define OFF_SPT 6307840      // SpT[NCH][BB][NN][DD]  = 4194304
#define OFF_AS  10502144     // As [NCH][BB][CH][CH]  = 1048576
// total = 11550720 floats = ~44.1 MB

// ---------------------------------------------------------------------------
// K1: w[s,n] = k[s,n] * exp(cumsum log(clip(alpha)))/ (exp(total)+EPS); pf = clip(alpha[0])
// thread per (c,b,n): sequential scan over s (matches reference order).
__global__ __launch_bounds__(256) void k_wpf(const float* __restrict__ kin,
                                             const float* __restrict__ alpha,
                                             float* __restrict__ w,
                                             float* __restrict__ pf) {
  int id = blockIdx.x * 256 + threadIdx.x;
  int n = id & (NN - 1);
  int b = (id >> 8) & (BB - 1);
  int c = id >> 10;
  const int stride = BB * NN;  // 1024
  size_t gbase = (size_t)(c * CH) * stride + b * NN + n;
  float ls = 0.f;
  for (int s = 0; s < CH; s++)
    ls += logf(fmaxf(alpha[gbase + (size_t)s * stride], EPSF));
  float denom = expf(ls) + EPSF;
  float run = 0.f;
  size_t wbase = ((size_t)(c * BB + b) * CH) * NN + n;
  for (int s = 0; s < CH; s++) {
    float av = fmaxf(alpha[gbase + (size_t)s * stride], EPSF);
    run += logf(av);
    float cp = expf(run);
    w[wbase + (size_t)s * NN] = kin[gbase + (size_t)s * stride] * (cp / denom);
  }
  pf[(c * BB + b) * NN + n] = fmaxf(alpha[gbase], EPSF);
}

// ---------------------------------------------------------------------------
// 4x4 micro-tile FMA helper (fully static indices after inlining)
__device__ __forceinline__ void fma4x4(float acc[4][4], const float* arow, const float* brow) {
  float4 a4 = *(const float4*)arow;
  float4 b4 = *(const float4*)brow;
  float ar[4] = {a4.x, a4.y, a4.z, a4.w};
  float br[4] = {b4.x, b4.y, b4.z, b4.w};
#pragma unroll
  for (int i = 0; i < 4; i++)
#pragma unroll
    for (int j = 0; j < 4; j++)
      acc[i][j] += ar[i] * br[j];
}

__device__ __forceinline__ void fma4x4_mask(float acc[4][4], const float* arow,
                                            const float* brow, int srel, int ty4) {
  float4 a4 = *(const float4*)arow;
  float4 b4 = *(const float4*)brow;
  float ar[4] = {a4.x, a4.y, a4.z, a4.w};
  float br[4] = {b4.x, b4.y, b4.z, b4.w};
#pragma unroll
  for (int i = 0; i < 4; i++) {
    float am = (ty4 + i >= srel) ? ar[i] : 0.f;
#pragma unroll
    for (int j = 0; j < 4; j++)
      acc[i][j] += am * br[j];
  }
}

// ---------------------------------------------------------------------------
// K2: UT[c,b,nn,dd] = sum_s w[s,nn]*v[s,dd].  64x64 tile, 4x4 micro, K=128.
__global__ __launch_bounds__(256) void k_ut(const float* __restrict__ v,
                                            const float* __restrict__ w,
                                            float* __restrict__ ut) {
  int bid = blockIdx.x;
  int nt = bid & 3, dt = (bid >> 2) & 3, b = (bid >> 4) & 3, c = bid >> 6;
  int tid = threadIdx.x;
  int ty = tid >> 4, tx = tid & 15;
  int n0 = nt * 64, d0 = dt * 64;
  __shared__ __align__(16) float wl[16][68];
  __shared__ __align__(16) float vl[16][68];
  float acc[4][4] = {};
  const float* wcb = w + (size_t)(c * BB + b) * CH * NN;
  int skk = tid >> 4, sdq = tid & 15;
  for (int k0 = 0; k0 < CH; k0 += 16) {
    __syncthreads();
    {
      float4 wv = *(const float4*)&wcb[(k0 + skk) * NN + n0 + sdq * 4];
      *(float4*)&wl[skk][sdq * 4] = wv;
      float4 vv = *(const float4*)&v[((size_t)(c * CH + k0 + skk) * BB + b) * DD + d0 + sdq * 4];
      *(float4*)&vl[skk][sdq * 4] = vv;
    }
    __syncthreads();
#pragma unroll
    for (int kk = 0; kk < 16; kk++)
      fma4x4(acc, &wl[kk][ty * 4], &vl[kk][tx * 4]);
  }
#pragma unroll
  for (int i = 0; i < 4; i++) {
    float4 o = {acc[i][0], acc[i][1], acc[i][2], acc[i][3]};
    *(float4*)&ut[((size_t)(c * BB + b) * NN + n0 + ty * 4 + i) * DD + d0 + tx * 4] = o;
  }
}

// ---------------------------------------------------------------------------
// K2b: As[c,b,s,t] = sum_n w[s,n]*q[t,n].  Lower-triangle 64x64 tiles (3 per (c,b)).
__global__ __launch_bounds__(256) void k_as(const float* __restrict__ w,
                                            const float* __restrict__ q,
                                            float* __restrict__ as_) {
  int bid = blockIdx.x;
  int tile = bid % 3;            // (si,ti) in {(0,0),(0,1),(1,1)}
  int cb = bid / 3;
  int b = cb & 3, c = cb >> 2;
  int si = (tile == 2) ? 1 : 0;
  int ti = (tile == 0) ? 0 : 1;
  int s0 = si * 64, t0 = ti * 64;
  int tid = threadIdx.x;
  int ty = tid >> 4, tx = tid & 15;
  __shared__ __align__(16) float wT[16][68];
  __shared__ __align__(16) float qT[16][68];
  float acc[4][4] = {};
  const float* wcb = w + (size_t)(c * BB + b) * CH * NN;
  int tr = tid >> 2, kq = tid & 3;
  for (int k0 = 0; k0 < NN; k0 += 16) {
    __syncthreads();
    {
      float4 wv = *(const float4*)&wcb[(s0 + tr) * NN + k0 + kq * 4];
      wT[kq * 4 + 0][tr] = wv.x;
      wT[kq * 4 + 1][tr] = wv.y;
      wT[kq * 4 + 2][tr] = wv.z;
      wT[kq * 4 + 3][tr] = wv.w;
      float4 qv = *(const float4*)&q[((size_t)(c * CH + t0 + tr) * BB + b) * NN + k0 + kq * 4];
      qT[kq * 4 + 0][tr] = qv.x;
      qT[kq * 4 + 1][tr] = qv.y;
      qT[kq * 4 + 2][tr] = qv.z;
      qT[kq * 4 + 3][tr] = qv.w;
    }
    __syncthreads();
#pragma unroll
    for (int kk = 0; kk < 16; kk++)
      fma4x4(acc, &wT[kk][ty * 4], &qT[kk][tx * 4]);
  }
#pragma unroll
  for (int i = 0; i < 4; i++) {
    float4 o = {acc[i][0], acc[i][1], acc[i][2], acc[i][3]};
    *(float4*)&as_[((size_t)(c * BB + b) * CH + s0 + ty * 4 + i) * CH + t0 + tx * 4] = o;
  }
}

// ---------------------------------------------------------------------------
// K3: per-element state scan over chunks. SpT[c,b,n,d] = incoming state of chunk c.
__global__ __launch_bounds__(256) void k_scan(const float* __restrict__ ut,
                                              const float* __restrict__ pf,
                                              float* __restrict__ spt) {
  int id = blockIdx.x * 256 + threadIdx.x;
  int dd = id & 255;
  int nn = (id >> 8) & 255;
  int b = id >> 16;
  float S = 0.f;
  for (int c = 0; c < NCH; c++) {
    size_t off = ((size_t)(c * BB + b) * NN + nn) * DD + dd;
    spt[off] = S;
    S = S * pf[(c * BB + b) * NN + nn] + ut[off];
  }
}

// ---------------------------------------------------------------------------
// K4: y[t,dd] = sum_n qp[t,n]*SpT[n,dd]  +  sum_{s<=t} As[s,t]*v[s,dd]
// 64(t) x 64(dd) tile, 4x4 micro.
__global__ __launch_bounds__(256) void k_out(const float* __restrict__ v,
                                             const float* __restrict__ q,
                                             const float* __restrict__ pf,
                                             const float* __restrict__ spt,
                                             const float* __restrict__ as_,
                                             float* __restrict__ y) {
  int bid = blockIdx.x;
  int dt = bid & 3, tt = (bid >> 2) & 1, b = (bid >> 3) & 3, c = bid >> 5;
  int t0 = tt * 64, d0 = dt * 64;
  int tid = threadIdx.x;
  int ty = tid >> 4, tx = tid & 15;
  __shared__ __align__(16) float al[16][68];
  __shared__ __align__(16) float bl[16][68];
  float acc[4][4] = {};
  int tr = tid >> 2, kq = tid & 3;
  int skk = tid >> 4, sdq = tid & 15;
  const float* spt_cb = spt + (size_t)(c * BB + b) * NN * DD;
  const float* pf_cb = pf + (c * BB + b) * NN;

  // Phase 1: inter-chunk  acc += qp[t,n] * SpT[n,dd],  K = NN
  for (int k0 = 0; k0 < NN; k0 += 16) {
    __syncthreads();
    {
      float4 qv = *(const float4*)&q[((size_t)(c * CH + t0 + tr) * BB + b) * NN + k0 + kq * 4];
      float4 pv = *(const float4*)&pf_cb[k0 + kq * 4];
      al[kq * 4 + 0][tr] = qv.x * pv.x;
      al[kq * 4 + 1][tr] = qv.y * pv.y;
      al[kq * 4 + 2][tr] = qv.z * pv.z;
      al[kq * 4 + 3][tr] = qv.w * pv.w;
      float4 sv = *(const float4*)&spt_cb[(size_t)(k0 + skk) * DD + d0 + sdq * 4];
      *(float4*)&bl[skk][sdq * 4] = sv;
    }
    __syncthreads();
#pragma unroll
    for (int kk = 0; kk < 16; kk++)
      fma4x4(acc, &al[kk][ty * 4], &bl[kk][tx * 4]);
  }

  // Phase 2: intra-chunk  acc += As[s,t]*v[s,dd] for s<=t,  K = t0+64
  const float* as_cb = as_ + (size_t)(c * BB + b) * CH * CH;
  int send = t0 + 64;
  int ty4 = ty * 4;
  for (int s0k = 0; s0k < send; s0k += 16) {
    __syncthreads();
    {
      float4 av = *(const float4*)&as_cb[(s0k + skk) * CH + t0 + sdq * 4];
      *(float4*)&al[skk][sdq * 4] = av;
      float4 vv = *(const float4*)&v[((size_t)(c * CH + s0k + skk) * BB + b) * DD + d0 + sdq * 4];
      *(float4*)&bl[skk][sdq * 4] = vv;
    }
    __syncthreads();
    if (s0k < t0) {
#pragma unroll
      for (int kk = 0; kk < 16; kk++)
        fma4x4(acc, &al[kk][ty * 4], &bl[kk][tx * 4]);
    } else {
#pragma unroll
      for (int kk = 0; kk < 16; kk++)
        fma4x4_mask(acc, &al[kk][ty * 4], &bl[kk][tx * 4], s0k + kk - t0, ty4);
    }
  }

#pragma unroll
  for (int i = 0; i < 4; i++) {
    float4 o = {acc[i][0], acc[i][1], acc[i][2], acc[i][3]};
    *(float4*)&y[((size_t)(c * CH + t0 + ty * 4 + i) * BB + b) * DD + d0 + tx * 4] = o;
  }
}

// ---------------------------------------------------------------------------
extern "C" void kernel_launch(void* const* d_in, const int* in_sizes, int n_in,
                              void* d_out, int out_size, void* d_ws, size_t ws_size,
                              hipStream_t stream) {
  const float* v = (const float*)d_in[0];
  const float* k = (const float*)d_in[1];
  const float* alpha = (const float*)d_in[2];
  const float* q = (const float*)d_in[3];
  float* y = (float*)d_out;
  float* ws = (float*)d_ws;
  float* w = ws + OFF_W;
  float* pf = ws + OFF_PF;
  float* ut = ws + OFF_UT;
  float* spt = ws + OFF_SPT;
  float* as_ = ws + OFF_AS;

  k_wpf<<<64, 256, 0, stream>>>(k, alpha, w, pf);
  k_ut<<<1024, 256, 0, stream>>>(v, w, ut);
  k_as<<<192, 256, 0, stream>>>(w, q, as_);
  k_scan<<<1024, 256, 0, stream>>>(ut, pf, spt);
  k_out<<<512, 256, 0, stream>>>(v, q, pf, spt, as_, y);
}

// Round 3
// 83.999 us; speedup vs baseline: 1.4614x; 1.4614x over previous
//
#include <hip/hip_runtime.h>
#include <math.h>

// Problem constants (from reference)
#define TT_  2048   // T
#define BB   4      // B
#define DD   256    // d
#define NN   256    // n
#define CH   128    // CHUNK
#define NCH  16     // T/CHUNK
#define EPSF 1e-8f

// Workspace layout (float offsets)
#define OFF_W   0            // w  [NCH][BB][CH][NN]  = 2097152
#define OFF_PF  2097152      // pf [NCH][BB][NN]      = 16384
#define OFF_UT  2113536      // UT [NCH][BB][NN][DD]  = 4194304
#define OFF_SPT 6307840      // SpT[NCH][BB][NN][DD]  = 4194304
#define OFF_AS  10502144     // As [NCH][BB][CH][CH]  = 1048576
// total = 11550720 floats = ~44.1 MB

// ---------------------------------------------------------------------------
// K1 (v2): segmented-scan parallelization of the per-(c,b,n) cumsum.
// Block = 256 threads = 16 segments (8 s-values each) x 16 n.
// grid = NCH*BB*16 = 1024 blocks (16 n-groups per (c,b)).
// w[s,n] = k[s,n] * exp(cumsum log(clip(alpha))) / (exp(total)+EPS)
// pf[n]  = clip(alpha[s=0,n])
__global__ __launch_bounds__(256) void k_wpf(const float* __restrict__ kin,
                                             const float* __restrict__ alpha,
                                             float* __restrict__ w,
                                             float* __restrict__ pf) {
  int bid = blockIdx.x;
  int ng = bid & 15;
  int b = (bid >> 4) & 3;
  int c = bid >> 6;
  int tid = threadIdx.x;
  int nn = tid & 15;
  int seg = tid >> 4;            // 0..15, each covers 8 consecutive s
  int n = ng * 16 + nn;
  const int stride = BB * NN;    // 1024
  size_t gbase = ((size_t)(c * CH + seg * 8) * stride) + b * NN + n;

  float lg[8];                   // local inclusive prefix of log(alpha)
  float kv[8];
  float a0 = 0.f;
  float run = 0.f;
#pragma unroll
  for (int i = 0; i < 8; i++) {
    float av = fmaxf(alpha[gbase + (size_t)i * stride], EPSF);
    kv[i] = kin[gbase + (size_t)i * stride];
    if (i == 0) a0 = av;
    run += __logf(av);
    lg[i] = run;
  }

  __shared__ float tot[16][17];
  tot[seg][nn] = run;
  __syncthreads();
  float prefix = 0.f, total = 0.f;
#pragma unroll
  for (int j = 0; j < 16; j++) {
    float tv = tot[j][nn];
    if (j < seg) prefix += tv;
    total += tv;
  }
  float rden = 1.f / (__expf(total) + EPSF);

  size_t wbase = ((size_t)(c * BB + b) * CH + seg * 8) * NN + n;
#pragma unroll
  for (int i = 0; i < 8; i++) {
    float cp = __expf(prefix + lg[i]);
    w[wbase + (size_t)i * NN] = kv[i] * (cp * rden);
  }
  if (seg == 0) pf[(c * BB + b) * NN + n] = a0;
}

// ---------------------------------------------------------------------------
// 4x4 micro-tile FMA helper (fully static indices after inlining)
__device__ __forceinline__ void fma4x4(float acc[4][4], const float* arow, const float* brow) {
  float4 a4 = *(const float4*)arow;
  float4 b4 = *(const float4*)brow;
  float ar[4] = {a4.x, a4.y, a4.z, a4.w};
  float br[4] = {b4.x, b4.y, b4.z, b4.w};
#pragma unroll
  for (int i = 0; i < 4; i++)
#pragma unroll
    for (int j = 0; j < 4; j++)
      acc[i][j] += ar[i] * br[j];
}

__device__ __forceinline__ void fma4x4_mask(float acc[4][4], const float* arow,
                                            const float* brow, int srel, int ty4) {
  float4 a4 = *(const float4*)arow;
  float4 b4 = *(const float4*)brow;
  float ar[4] = {a4.x, a4.y, a4.z, a4.w};
  float br[4] = {b4.x, b4.y, b4.z, b4.w};
#pragma unroll
  for (int i = 0; i < 4; i++) {
    float am = (ty4 + i >= srel) ? ar[i] : 0.f;
#pragma unroll
    for (int j = 0; j < 4; j++)
      acc[i][j] += am * br[j];
  }
}

// ---------------------------------------------------------------------------
// K2: UT[c,b,nn,dd] = sum_s w[s,nn]*v[s,dd].  64x64 tile, 4x4 micro, K=128.
__global__ __launch_bounds__(256) void k_ut(const float* __restrict__ v,
                                            const float* __restrict__ w,
                                            float* __restrict__ ut) {
  int bid = blockIdx.x;
  int nt = bid & 3, dt = (bid >> 2) & 3, b = (bid >> 4) & 3, c = bid >> 6;
  int tid = threadIdx.x;
  int ty = tid >> 4, tx = tid & 15;
  int n0 = nt * 64, d0 = dt * 64;
  __shared__ __align__(16) float wl[16][68];
  __shared__ __align__(16) float vl[16][68];
  float acc[4][4] = {};
  const float* wcb = w + (size_t)(c * BB + b) * CH * NN;
  int skk = tid >> 4, sdq = tid & 15;
  for (int k0 = 0; k0 < CH; k0 += 16) {
    __syncthreads();
    {
      float4 wv = *(const float4*)&wcb[(k0 + skk) * NN + n0 + sdq * 4];
      *(float4*)&wl[skk][sdq * 4] = wv;
      float4 vv = *(const float4*)&v[((size_t)(c * CH + k0 + skk) * BB + b) * DD + d0 + sdq * 4];
      *(float4*)&vl[skk][sdq * 4] = vv;
    }
    __syncthreads();
#pragma unroll
    for (int kk = 0; kk < 16; kk++)
      fma4x4(acc, &wl[kk][ty * 4], &vl[kk][tx * 4]);
  }
#pragma unroll
  for (int i = 0; i < 4; i++) {
    float4 o = {acc[i][0], acc[i][1], acc[i][2], acc[i][3]};
    *(float4*)&ut[((size_t)(c * BB + b) * NN + n0 + ty * 4 + i) * DD + d0 + tx * 4] = o;
  }
}

// ---------------------------------------------------------------------------
// K2b: As[c,b,s,t] = sum_n w[s,n]*q[t,n].  Lower-triangle 64x64 tiles (3 per (c,b)).
__global__ __launch_bounds__(256) void k_as(const float* __restrict__ w,
                                            const float* __restrict__ q,
                                            float* __restrict__ as_) {
  int bid = blockIdx.x;
  int tile = bid % 3;            // (si,ti) in {(0,0),(0,1),(1,1)}
  int cb = bid / 3;
  int b = cb & 3, c = cb >> 2;
  int si = (tile == 2) ? 1 : 0;
  int ti = (tile == 0) ? 0 : 1;
  int s0 = si * 64, t0 = ti * 64;
  int tid = threadIdx.x;
  int ty = tid >> 4, tx = tid & 15;
  __shared__ __align__(16) float wT[16][68];
  __shared__ __align__(16) float qT[16][68];
  float acc[4][4] = {};
  const float* wcb = w + (size_t)(c * BB + b) * CH * NN;
  int tr = tid >> 2, kq = tid & 3;
  for (int k0 = 0; k0 < NN; k0 += 16) {
    __syncthreads();
    {
      float4 wv = *(const float4*)&wcb[(s0 + tr) * NN + k0 + kq * 4];
      wT[kq * 4 + 0][tr] = wv.x;
      wT[kq * 4 + 1][tr] = wv.y;
      wT[kq * 4 + 2][tr] = wv.z;
      wT[kq * 4 + 3][tr] = wv.w;
      float4 qv = *(const float4*)&q[((size_t)(c * CH + t0 + tr) * BB + b) * NN + k0 + kq * 4];
      qT[kq * 4 + 0][tr] = qv.x;
      qT[kq * 4 + 1][tr] = qv.y;
      qT[kq * 4 + 2][tr] = qv.z;
      qT[kq * 4 + 3][tr] = qv.w;
    }
    __syncthreads();
#pragma unroll
    for (int kk = 0; kk < 16; kk++)
      fma4x4(acc, &wT[kk][ty * 4], &qT[kk][tx * 4]);
  }
#pragma unroll
  for (int i = 0; i < 4; i++) {
    float4 o = {acc[i][0], acc[i][1], acc[i][2], acc[i][3]};
    *(float4*)&as_[((size_t)(c * BB + b) * CH + s0 + ty * 4 + i) * CH + t0 + tx * 4] = o;
  }
}

// ---------------------------------------------------------------------------
// K3: per-element state scan over chunks. SpT[c,b,n,d] = incoming state of chunk c.
__global__ __launch_bounds__(256) void k_scan(const float* __restrict__ ut,
                                              const float* __restrict__ pf,
                                              float* __restrict__ spt) {
  int id = blockIdx.x * 256 + threadIdx.x;
  int dd = id & 255;
  int nn = (id >> 8) & 255;
  int b = id >> 16;
  float S = 0.f;
  for (int c = 0; c < NCH; c++) {
    size_t off = ((size_t)(c * BB + b) * NN + nn) * DD + dd;
    spt[off] = S;
    S = S * pf[(c * BB + b) * NN + nn] + ut[off];
  }
}

// ---------------------------------------------------------------------------
// K4: y[t,dd] = sum_n qp[t,n]*SpT[n,dd]  +  sum_{s<=t} As[s,t]*v[s,dd]
// 64(t) x 64(dd) tile, 4x4 micro.
__global__ __launch_bounds__(256) void k_out(const float* __restrict__ v,
                                             const float* __restrict__ q,
                                             const float* __restrict__ pf,
                                             const float* __restrict__ spt,
                                             const float* __restrict__ as_,
                                             float* __restrict__ y) {
  int bid = blockIdx.x;
  int dt = bid & 3, tt = (bid >> 2) & 1, b = (bid >> 3) & 3, c = bid >> 5;
  int t0 = tt * 64, d0 = dt * 64;
  int tid = threadIdx.x;
  int ty = tid >> 4, tx = tid & 15;
  __shared__ __align__(16) float al[16][68];
  __shared__ __align__(16) float bl[16][68];
  float acc[4][4] = {};
  int tr = tid >> 2, kq = tid & 3;
  int skk = tid >> 4, sdq = tid & 15;
  const float* spt_cb = spt + (size_t)(c * BB + b) * NN * DD;
  const float* pf_cb = pf + (c * BB + b) * NN;

  // Phase 1: inter-chunk  acc += qp[t,n] * SpT[n,dd],  K = NN
  for (int k0 = 0; k0 < NN; k0 += 16) {
    __syncthreads();
    {
      float4 qv = *(const float4*)&q[((size_t)(c * CH + t0 + tr) * BB + b) * NN + k0 + kq * 4];
      float4 pv = *(const float4*)&pf_cb[k0 + kq * 4];
      al[kq * 4 + 0][tr] = qv.x * pv.x;
      al[kq * 4 + 1][tr] = qv.y * pv.y;
      al[kq * 4 + 2][tr] = qv.z * pv.z;
      al[kq * 4 + 3][tr] = qv.w * pv.w;
      float4 sv = *(const float4*)&spt_cb[(size_t)(k0 + skk) * DD + d0 + sdq * 4];
      *(float4*)&bl[skk][sdq * 4] = sv;
    }
    __syncthreads();
#pragma unroll
    for (int kk = 0; kk < 16; kk++)
      fma4x4(acc, &al[kk][ty * 4], &bl[kk][tx * 4]);
  }

  // Phase 2: intra-chunk  acc += As[s,t]*v[s,dd] for s<=t,  K = t0+64
  const float* as_cb = as_ + (size_t)(c * BB + b) * CH * CH;
  int send = t0 + 64;
  int ty4 = ty * 4;
  for (int s0k = 0; s0k < send; s0k += 16) {
    __syncthreads();
    {
      float4 av = *(const float4*)&as_cb[(s0k + skk) * CH + t0 + sdq * 4];
      *(float4*)&al[skk][sdq * 4] = av;
      float4 vv = *(const float4*)&v[((size_t)(c * CH + s0k + skk) * BB + b) * DD + d0 + sdq * 4];
      *(float4*)&bl[skk][sdq * 4] = vv;
    }
    __syncthreads();
    if (s0k < t0) {
#pragma unroll
      for (int kk = 0; kk < 16; kk++)
        fma4x4(acc, &al[kk][ty * 4], &bl[kk][tx * 4]);
    } else {
#pragma unroll
      for (int kk = 0; kk < 16; kk++)
        fma4x4_mask(acc, &al[kk][ty * 4], &bl[kk][tx * 4], s0k + kk - t0, ty4);
    }
  }

#pragma unroll
  for (int i = 0; i < 4; i++) {
    float4 o = {acc[i][0], acc[i][1], acc[i][2], acc[i][3]};
    *(float4*)&y[((size_t)(c * CH + t0 + ty * 4 + i) * BB + b) * DD + d0 + tx * 4] = o;
  }
}

// ---------------------------------------------------------------------------
extern "C" void kernel_launch(void* const* d_in, const int* in_sizes, int n_in,
                              void* d_out, int out_size, void* d_ws, size_t ws_size,
                              hipStream_t stream) {
  const float* v = (const float*)d_in[0];
  const float* k = (const float*)d_in[1];
  const float* alpha = (const float*)d_in[2];
  const float* q = (const float*)d_in[3];
  float* y = (float*)d_out;
  float* ws = (float*)d_ws;
  float* w = ws + OFF_W;
  float* pf = ws + OFF_PF;
  float* ut = ws + OFF_UT;
  float* spt = ws + OFF_SPT;
  float* as_ = ws + OFF_AS;

  k_wpf<<<1024, 256, 0, stream>>>(k, alpha, w, pf);
  k_ut<<<1024, 256, 0, stream>>>(v, w, ut);
  k_as<<<192, 256, 0, stream>>>(w, q, as_);
  k_scan<<<1024, 256, 0, stream>>>(ut, pf, spt);
  k_out<<<512, 256, 0, stream>>>(v, q, pf, spt, as_, y);
}

// Round 8
// 51.884 us; speedup vs baseline: 2.3660x; 1.6190x over previous
//
#include <hip/hip_runtime.h>
#include <math.h>

typedef unsigned short u16;
typedef unsigned int u32;
typedef __bf16 bf16x8 __attribute__((ext_vector_type(8)));
typedef float f32x4 __attribute__((ext_vector_type(4)));

// Problem constants
#define BB   4      // B
#define DD   256    // d
#define NN   256    // n
#define CH   128    // CHUNK
#define NCH  16     // T/CHUNK
#define EPSF 1e-8f

// Workspace byte offsets
#define WS_QB  0u           // qb   bf16 [T][B][N]          4 MB
#define WS_VT  (4u<<20)     // vT   bf16 [CB][D][S=128]     4 MB
#define WS_WT  (8u<<20)     // wT   bf16 [CB][N][S=128]     4 MB
#define WS_WN  (12u<<20)    // w_n  bf16 [CB][S][N]         4 MB
#define WS_AST (16u<<20)    // AsT  bf16 [CB][T=128][S=128] 2 MB
#define WS_SPT (18u<<20)    // sptT bf16 [CB][D][N]         8 MB
#define WS_PF  (26u<<20)    // pf   f32  [CB][N]            64 KB
#define WS_UTT (28u<<20)    // utT  f32  [CB][D][N]         16 MB

__device__ __forceinline__ u16 f2bf(float x) {
  u32 u = __float_as_uint(x);
  u32 r = (u + 0x7fffu + ((u >> 16) & 1u)) >> 16;
  return (u16)r;
}

__device__ __forceinline__ void gload16(void* lds, const void* g) {
  __builtin_amdgcn_global_load_lds((const __attribute__((address_space(1))) void*)g,
                                   (__attribute__((address_space(3))) void*)lds, 16, 0, 0);
}

// Stage a 64x64 bf16 tile (row-major, rowstride in elems) into linear LDS.
// LDS dest is linear (wave-uniform base + lane*16); the slot-XOR swizzle is
// applied on the GLOBAL source address (m173 pattern). 256 thr x 2 chunks.
__device__ __forceinline__ void stage_tile(u16* lds, const u16* g, int rowstride) {
  int tid = threadIdx.x;
#pragma unroll
  for (int h = 0; h < 2; h++) {
    int ci = tid + h * 256;
    int r = ci >> 3, sl = ci & 7;
    const u16* src = g + (size_t)r * rowstride + ((sl ^ (r & 7)) << 3);
    gload16(lds + (size_t)ci * 8, src);
  }
}

// Read 2x2 fragments (rows rbase..+32, K=64 in two 32-subs) with matching swizzle.
// FIX (R7): chunk index is ks*4 + (lane>>4) -- (ks<<1) was non-bijective
// (k 32..63 never read, k 16..47 double-counted in every GEMM).
__device__ __forceinline__ void read_frags(const u16* buf, int rbase, int lane,
                                           bf16x8 (&f)[2][2]) {
#pragma unroll
  for (int i = 0; i < 2; i++)
#pragma unroll
    for (int ks = 0; ks < 2; ks++) {
      int r = rbase + i * 16 + (lane & 15);
      int slot = ((ks << 2) + (lane >> 4)) ^ (r & 7);
      f[i][ks] = *reinterpret_cast<const bf16x8*>(buf + r * 64 + slot * 8);
    }
}

__device__ __forceinline__ void mma_step(const u16* Ab, const u16* Bb, int rm, int cn,
                                         int lane, f32x4 (&acc)[2][2]) {
  bf16x8 a[2][2], b[2][2];
  read_frags(Ab, rm, lane, a);
  read_frags(Bb, cn, lane, b);
#pragma unroll
  for (int mf = 0; mf < 2; mf++)
#pragma unroll
    for (int nf = 0; nf < 2; nf++)
#pragma unroll
      for (int ks = 0; ks < 2; ks++)
        acc[mf][nf] = __builtin_amdgcn_mfma_f32_16x16x32_bf16(a[mf][ks], b[nf][ks],
                                                              acc[mf][nf], 0, 0, 0);
}

// ---------------------------------------------------------------------------
// q (fp32) -> qb (bf16), same layout. 1024 blocks x 256, 8 elems/thread.
__global__ __launch_bounds__(256) void k_convq(const float* __restrict__ q,
                                               u16* __restrict__ qb) {
  size_t gid = (size_t)blockIdx.x * 256 + threadIdx.x;
  const float4* src = (const float4*)q + gid * 2;
  float4 x = src[0], z = src[1];
  union { u16 u[8]; uint4 v4; } pk;
  pk.u[0] = f2bf(x.x); pk.u[1] = f2bf(x.y); pk.u[2] = f2bf(x.z); pk.u[3] = f2bf(x.w);
  pk.u[4] = f2bf(z.x); pk.u[5] = f2bf(z.y); pk.u[6] = f2bf(z.z); pk.u[7] = f2bf(z.w);
  ((uint4*)qb)[gid] = pk.v4;
}

// ---------------------------------------------------------------------------
// v [t][b][d] fp32 -> vT [cb][d][s] bf16 (transpose via LDS). 256 blocks.
// FIX (R6): output phase writes 4 uint4 = 32 u16 per thread.
__global__ __launch_bounds__(256) void k_trv(const float* __restrict__ v,
                                             u16* __restrict__ vT) {
  int bid = blockIdx.x;
  int dt = bid & 3, cb = bid >> 2;
  int c = cb >> 2, b = cb & 3;
  int d0 = dt * 64;
  __shared__ u16 vt[64 * 136];
  int tid = threadIdx.x;
  int sr = tid >> 4, chd = tid & 15;
#pragma unroll
  for (int p = 0; p < 8; p++) {
    int s = p * 16 + sr;
    float4 x = *(const float4*)&v[((size_t)(c * CH + s) * BB + b) * DD + d0 + chd * 4];
    int dbase = chd * 4;
    vt[(dbase + 0) * 136 + s] = f2bf(x.x);
    vt[(dbase + 1) * 136 + s] = f2bf(x.y);
    vt[(dbase + 2) * 136 + s] = f2bf(x.z);
    vt[(dbase + 3) * 136 + s] = f2bf(x.w);
  }
  __syncthreads();
  int dr = tid >> 2, ch = tid & 3;
  const uint4* srcl = (const uint4*)&vt[dr * 136 + ch * 32];
  uint4 a0 = srcl[0], a1 = srcl[1], a2 = srcl[2], a3 = srcl[3];
  uint4* dst = (uint4*)&vT[((size_t)cb * DD + d0 + dr) * CH + ch * 32];
  dst[0] = a0; dst[1] = a1; dst[2] = a2; dst[3] = a3;
}

// ---------------------------------------------------------------------------
// k_wpf: segmented scan; writes wT bf16 [n][s], w_n bf16 [s][n], pf f32.
__global__ __launch_bounds__(256) void k_wpf(const float* __restrict__ kin,
                                             const float* __restrict__ alpha,
                                             u16* __restrict__ wT,
                                             u16* __restrict__ wn,
                                             float* __restrict__ pf) {
  int bid = blockIdx.x;
  int ng = bid & 15;
  int b = (bid >> 4) & 3;
  int c = bid >> 6;
  int tid = threadIdx.x;
  int nn = tid & 15;
  int seg = tid >> 4;
  int n = ng * 16 + nn;
  int cb = c * BB + b;
  const int stride = BB * NN;
  size_t gbase = ((size_t)(c * CH + seg * 8) * stride) + b * NN + n;

  float lg[8], kv[8];
  float a0 = 0.f, run = 0.f;
#pragma unroll
  for (int i = 0; i < 8; i++) {
    float av = fmaxf(alpha[gbase + (size_t)i * stride], EPSF);
    kv[i] = kin[gbase + (size_t)i * stride];
    if (i == 0) a0 = av;
    run += __logf(av);
    lg[i] = run;
  }

  __shared__ float tot[16][17];
  tot[seg][nn] = run;
  __syncthreads();
  float prefix = 0.f, total = 0.f;
#pragma unroll
  for (int j = 0; j < 16; j++) {
    float tv = tot[j][nn];
    if (j < seg) prefix += tv;
    total += tv;
  }
  float rden = 1.f / (__expf(total) + EPSF);

  union { u16 u[8]; uint4 v4; } pk;
  u16* wnrow = wn + (size_t)cb * (CH * NN) + n;
#pragma unroll
  for (int i = 0; i < 8; i++) {
    float cp = __expf(prefix + lg[i]);
    u16 h = f2bf(kv[i] * (cp * rden));
    pk.u[i] = h;
    wnrow[(size_t)(seg * 8 + i) * NN] = h;
  }
  *(uint4*)(wT + (size_t)cb * (NN * CH) + (size_t)n * CH + seg * 8) = pk.v4;
  if (seg == 0) pf[cb * NN + n] = a0;
}

// ---------------------------------------------------------------------------
// k_ut (MFMA): utT[cb][d][n] = sum_s vT[d,s]*wT[n,s].  K=128. 1024 blocks.
__global__ __launch_bounds__(256) void k_ut(const u16* __restrict__ vT,
                                            const u16* __restrict__ wT,
                                            float* __restrict__ utT) {
  int bid = blockIdx.x;
  int nt = bid & 3, dt = (bid >> 2) & 3, cb = bid >> 4;
  int tid = threadIdx.x, lane = tid & 63, wv = tid >> 6;
  int rm = (wv >> 1) * 32, cn = (wv & 1) * 32;
  const u16* A = vT + ((size_t)cb * DD + dt * 64) * CH;
  const u16* B = wT + ((size_t)cb * NN + nt * 64) * CH;
  __shared__ u16 Al[2][4096], Bl[2][4096];
  f32x4 acc[2][2] = {};
  stage_tile(Al[0], A, CH); stage_tile(Bl[0], B, CH);
  __syncthreads();
  stage_tile(Al[1], A + 64, CH); stage_tile(Bl[1], B + 64, CH);
  mma_step(Al[0], Bl[0], rm, cn, lane, acc);
  __syncthreads();
  mma_step(Al[1], Bl[1], rm, cn, lane, acc);
  float* out = utT + ((size_t)cb * DD + dt * 64) * NN + nt * 64;
#pragma unroll
  for (int mf = 0; mf < 2; mf++)
#pragma unroll
    for (int nf = 0; nf < 2; nf++)
#pragma unroll
      for (int r = 0; r < 4; r++) {
        int row = rm + mf * 16 + (lane >> 4) * 4 + r;
        int col = cn + nf * 16 + (lane & 15);
        out[(size_t)row * NN + col] = acc[mf][nf][r];
      }
}

// ---------------------------------------------------------------------------
// k_as (MFMA): AsT[cb][t][s] = mask(s<=t) * sum_n qb[t,n]*w_n[s,n].  K=256.
// 3 tiles per cb (skip never-read zero quadrant). 192 blocks.
__global__ __launch_bounds__(256) void k_as(const u16* __restrict__ qb,
                                            const u16* __restrict__ wn,
                                            u16* __restrict__ asT) {
  int bid = blockIdx.x;
  int tile = bid % 3;
  int cb = bid / 3;
  int ti = (tile == 0) ? 0 : 1;
  int si = (tile == 2) ? 1 : 0;
  int t0 = ti * 64, s0 = si * 64;
  int c = cb >> 2, b = cb & 3;
  int tid = threadIdx.x, lane = tid & 63, wv = tid >> 6;
  int rm = (wv >> 1) * 32, cn = (wv & 1) * 32;
  const u16* A = qb + ((size_t)(c * CH + t0) * BB + b) * NN;   // stride 1024
  const u16* B = wn + (size_t)cb * (CH * NN) + (size_t)s0 * NN; // stride 256
  __shared__ u16 Al[2][4096], Bl[2][4096];
  f32x4 acc[2][2] = {};
  stage_tile(Al[0], A, BB * NN); stage_tile(Bl[0], B, NN);
  __syncthreads();
  for (int st = 0; st < 4; st++) {
    int nx = st + 1;
    if (nx < 4) {
      stage_tile(Al[nx & 1], A + nx * 64, BB * NN);
      stage_tile(Bl[nx & 1], B + nx * 64, NN);
    }
    mma_step(Al[st & 1], Bl[st & 1], rm, cn, lane, acc);
    __syncthreads();
  }
  u16* outb = asT + (size_t)cb * (CH * CH);
#pragma unroll
  for (int mf = 0; mf < 2; mf++)
#pragma unroll
    for (int nf = 0; nf < 2; nf++)
#pragma unroll
      for (int r = 0; r < 4; r++) {
        int t = t0 + rm + mf * 16 + (lane >> 4) * 4 + r;
        int s = s0 + cn + nf * 16 + (lane & 15);
        float val = (s <= t) ? acc[mf][nf][r] : 0.f;
        outb[(size_t)t * CH + s] = f2bf(val);
      }
}

// ---------------------------------------------------------------------------
// k_scan: S=0; per chunk: Sp = S*pf; sptT = bf16(Sp); S = Sp + utT. 1024 blocks.
__global__ __launch_bounds__(256) void k_scan(const float* __restrict__ utT,
                                              const float* __restrict__ pf,
                                              u16* __restrict__ sptT) {
  int id = blockIdx.x * 256 + threadIdx.x;
  int nn = id & 255, dd = (id >> 8) & 255, b = id >> 16;
  float S = 0.f;
  for (int ch = 0; ch < NCH; ch++) {
    int cb = ch * BB + b;
    size_t off = ((size_t)cb * DD + dd) * NN + nn;
    float p = pf[cb * NN + nn];
    float Sp = S * p;
    sptT[off] = f2bf(Sp);
    S = Sp + utT[off];
  }
}

// ---------------------------------------------------------------------------
// k_out (MFMA): y[t,d] = sum_n qb[t,n]*sptT[d,n] + sum_s AsT[t,s]*vT[d,s].
// K = 256 + (64 or 128). 512 blocks.
__global__ __launch_bounds__(256) void k_out(const u16* __restrict__ qb,
                                             const u16* __restrict__ sptT,
                                             const u16* __restrict__ asT,
                                             const u16* __restrict__ vT,
                                             float* __restrict__ y) {
  int bid = blockIdx.x;
  int dt = bid & 3, tt = (bid >> 2) & 1, cb = bid >> 3;
  int c = cb >> 2, b = cb & 3;
  int t0 = tt * 64, d0 = dt * 64;
  int tid = threadIdx.x, lane = tid & 63, wv = tid >> 6;
  int rm = (wv >> 1) * 32, cn = (wv & 1) * 32;
  const u16* A1 = qb + ((size_t)(c * CH + t0) * BB + b) * NN;      // stride 1024
  const u16* B1 = sptT + ((size_t)cb * DD + d0) * NN;              // stride 256
  const u16* A2 = asT + (size_t)cb * (CH * CH) + (size_t)t0 * CH;  // stride 128
  const u16* B2 = vT + ((size_t)cb * DD + d0) * CH;                // stride 128
  __shared__ u16 Al[2][4096], Bl[2][4096];
  f32x4 acc[2][2] = {};
  int nst = 5 + tt;  // tt=0: s in [0,64) only (rest masked to zero, never read)
  stage_tile(Al[0], A1, BB * NN); stage_tile(Bl[0], B1, NN);
  __syncthreads();
  for (int st = 0; st < nst; st++) {
    int nx = st + 1;
    if (nx < 4) {
      stage_tile(Al[nx & 1], A1 + nx * 64, BB * NN);
      stage_tile(Bl[nx & 1], B1 + nx * 64, NN);
    } else if (nx < nst) {
      stage_tile(Al[nx & 1], A2 + (nx - 4) * 64, CH);
      stage_tile(Bl[nx & 1], B2 + (nx - 4) * 64, CH);
    }
    mma_step(Al[st & 1], Bl[st & 1], rm, cn, lane, acc);
    __syncthreads();
  }
  float* out = y + ((size_t)(c * CH + t0) * BB + b) * DD + d0;
#pragma unroll
  for (int mf = 0; mf < 2; mf++)
#pragma unroll
    for (int nf = 0; nf < 2; nf++)
#pragma unroll
      for (int r = 0; r < 4; r++) {
        int row = rm + mf * 16 + (lane >> 4) * 4 + r;
        int col = cn + nf * 16 + (lane & 15);
        out[(size_t)row * (BB * DD) + col] = acc[mf][nf][r];
      }
}

// ---------------------------------------------------------------------------
extern "C" void kernel_launch(void* const* d_in, const int* in_sizes, int n_in,
                              void* d_out, int out_size, void* d_ws, size_t ws_size,
                              hipStream_t stream) {
  const float* v = (const float*)d_in[0];
  const float* k = (const float*)d_in[1];
  const float* alpha = (const float*)d_in[2];
  const float* q = (const float*)d_in[3];
  float* y = (float*)d_out;
  char* ws = (char*)d_ws;
  u16* qb = (u16*)(ws + WS_QB);
  u16* vT = (u16*)(ws + WS_VT);
  u16* wT = (u16*)(ws + WS_WT);
  u16* wn = (u16*)(ws + WS_WN);
  u16* asT = (u16*)(ws + WS_AST);
  u16* sptT = (u16*)(ws + WS_SPT);
  float* pf = (float*)(ws + WS_PF);
  float* utT = (float*)(ws + WS_UTT);

  k_convq<<<1024, 256, 0, stream>>>(q, qb);
  k_trv<<<256, 256, 0, stream>>>(v, vT);
  k_wpf<<<1024, 256, 0, stream>>>(k, alpha, wT, wn, pf);
  k_ut<<<1024, 256, 0, stream>>>(vT, wT, utT);
  k_as<<<192, 256, 0, stream>>>(qb, wn, asT);
  k_scan<<<1024, 256, 0, stream>>>(utT, pf, sptT);
  k_out<<<512, 256, 0, stream>>>(qb, sptT, asT, vT, y);
}